// Round 13
// baseline (1044.019 us; speedup 1.0000x reference)
//
#include <hip/hip_runtime.h>
#include <math.h>

#define CDIM 32
#define HWDIM 2304            // 48*48
#define BDIM 16
#define PPW 8                 // pixels per wave (8 lanes per pixel)
#define NTHREADS 256          // 4 waves => 32 pixels per block
#define PPB 32
#define ZOFF (BDIM * CDIM * HWDIM)   // z elements, then 16 logdet floats

// R12 lesson: packed-math inline asm ("+v" tied f32x2) wrecked regalloc
// (WRITE 1.9GB). Clean lineage only: R3 staging + R3 right-looking algebra
// + R7 DPP bcast8, (256,2), single batch.
// R13 theory: R7's 114us closes as 3100 instr x 2cy = 6.2K cy/wave issue
// = 25% of runtime = measured VALUBusy; 75% is dependency stall. R7's
// LEFT-looking body is serial per column (bcast reads what the previous
// link just wrote). Fix = right-looking order (all j independent within a
// k-step) + explicit 4-wide broadcast batches: 8 independent DPP movs then
// 10 independent fmas, one chain-stall amortized over 4 columns. Pure
// reorder, +4 regs; discriminates dependency-bound (big win) vs I$-bound
// (null).
__device__ __forceinline__ void gload_lds16(const float* g, float* l) {
    __builtin_amdgcn_global_load_lds(
        (const __attribute__((address_space(1))) float*)g,
        (__attribute__((address_space(3))) float*)l, 16, 0, 0);
}

// Broadcast lane (group_base + k7) to all 8 lanes of each aligned 8-lane
// group (R7-proven DPP pair; k7 compile-time, call sites fully unrolled).
// Step1 quad_perm([s,s,s,s]), s=k7&3. Step2: k7<4: row_shr:4 mask 0xA
// (odd quads <- even); k7>=4: row_shl:4 mask 0x5 (even <- odd).
__device__ __forceinline__ float bcast8(float x, int k7) {
    int v = __float_as_int(x), b;
    switch (k7) {
    case 0: b = __builtin_amdgcn_update_dpp(v, v, 0x00, 0xF, 0xF, false);
            b = __builtin_amdgcn_update_dpp(b, b, 0x114, 0xF, 0xA, false); break;
    case 1: b = __builtin_amdgcn_update_dpp(v, v, 0x55, 0xF, 0xF, false);
            b = __builtin_amdgcn_update_dpp(b, b, 0x114, 0xF, 0xA, false); break;
    case 2: b = __builtin_amdgcn_update_dpp(v, v, 0xAA, 0xF, 0xF, false);
            b = __builtin_amdgcn_update_dpp(b, b, 0x114, 0xF, 0xA, false); break;
    case 3: b = __builtin_amdgcn_update_dpp(v, v, 0xFF, 0xF, 0xF, false);
            b = __builtin_amdgcn_update_dpp(b, b, 0x114, 0xF, 0xA, false); break;
    case 4: b = __builtin_amdgcn_update_dpp(v, v, 0x00, 0xF, 0xF, false);
            b = __builtin_amdgcn_update_dpp(b, b, 0x104, 0xF, 0x5, false); break;
    case 5: b = __builtin_amdgcn_update_dpp(v, v, 0x55, 0xF, 0xF, false);
            b = __builtin_amdgcn_update_dpp(b, b, 0x104, 0xF, 0x5, false); break;
    case 6: b = __builtin_amdgcn_update_dpp(v, v, 0xAA, 0xF, 0xF, false);
            b = __builtin_amdgcn_update_dpp(b, b, 0x104, 0xF, 0x5, false); break;
    default: b = __builtin_amdgcn_update_dpp(v, v, 0xFF, 0xF, 0xF, false);
            b = __builtin_amdgcn_update_dpp(b, b, 0x104, 0xF, 0x5, false); break;
    }
    return __int_as_float(b);
}

__global__ __launch_bounds__(NTHREADS, 2)
void solve_kernel(const float* __restrict__ input,
                  const float* __restrict__ weight,
                  const float* __restrict__ logdet,
                  float* __restrict__ out) {
    const int t    = threadIdx.x;
    const int lane = t & 63;
    const int wv   = t >> 6;           // wave 0..3
    const int h    = lane & 7;         // row class: owns rows i = 8r + h
    const int p    = lane >> 3;        // pixel-in-wave 0..7

    const int blk  = blockIdx.x;
    const int b    = blk / (HWDIM / PPB);       // 72 blocks per batch image
    const int pb   = (blk % (HWDIM / PPB)) * PPB;  // block pixel base
    const int pixl = wv * PPW + p;              // pixel-in-block 0..31
    const int pix0 = pb + wv * PPW;             // wave pixel base (logdet cond)
    const int pix  = pb + pixl;

    __shared__ float lds[2][256 * CDIM];        // 2 x 32KB chunk ring

    // ---- x: scalar loads, issued first (oldest in vmcnt order) ----
    const float* xp = input + (size_t)b * CDIM * HWDIM + (size_t)h * HWDIM + pix;
    float y[4];
    #pragma unroll
    for (int r = 0; r < 4; ++r) y[r] = xp[(size_t)(r * 8) * HWDIM];
    asm volatile("" ::: "memory");     // pin: x loads oldest in vmcnt order

    // ---- DMA staging (R3-verbatim): chunk r = rc-rows [256r, 256r+256) ----
    // rcl = wv*64 + q*8 + sg; LDS dest linear (word rcl*32 + sp*4); global
    // source slot pre-swizzled by g = rcl>>5 (wave-uniform per q -> full
    // 128B lines). Read: A[r][j] at word (h*32+j)*32 + ((ps^h)<<2)+pc.
    const int sg = lane >> 3;
    const int sp = lane & 7;
    const int ps = pixl >> 2, pc = pixl & 3;
    const float* wbase = weight + (size_t)b * (CDIM * CDIM) * HWDIM + pb;
    const float* srcA = wbase + (size_t)(wv * 64 + sg) * HWDIM
                              + ((sp ^ (2 * wv)) << 2);
    const float* srcB = wbase + (size_t)(wv * 64 + sg) * HWDIM
                              + ((sp ^ (2 * wv + 1)) << 2);

    auto stage = [&](int r, int buf) {
        float* lbase = &lds[buf][(wv * 64) * CDIM];
        #pragma unroll
        for (int q = 0; q < 8; ++q) {
            const float* s = (q < 4 ? srcA : srcB)
                           + (size_t)(r * 256 + q * 8) * HWDIM;
            gload_lds16(s, lbase + q * 8 * CDIM);
        }
    };

    stage(0, 0);
    asm volatile("" ::: "memory");
    stage(1, 1);

    float A[4][CDIM];
    #pragma unroll
    for (int r = 0; r < 4; ++r) {
        if (r < 3) asm volatile("s_waitcnt vmcnt(8)" ::: "memory");
        else       asm volatile("s_waitcnt vmcnt(0)" ::: "memory");
        __builtin_amdgcn_s_barrier();
        asm volatile("" ::: "memory");
        #pragma unroll
        for (int j = 0; j < CDIM; ++j)
            A[r][j] = lds[r & 1][(h * CDIM + j) * CDIM + ((ps ^ h) << 2) + pc];
        if (r < 2) {
            asm volatile("s_waitcnt lgkmcnt(0)" ::: "memory");
            __builtin_amdgcn_s_barrier();
            asm volatile("" ::: "memory");
            stage(r + 2, r & 1);
        }
    }

    // ---- right-looking LU, no pivoting (R3-verbatim algebra; owner row
    // scaled to unit diagonal via m_owner = 1-r). 4-wide j-batches give the
    // in-order wave 8 independent DPP movs + 10 independent fmas per batch.
    float lacc = 0.0f;
    #pragma unroll
    for (int k = 0; k < CDIM; ++k) {
        const int tr = k >> 3, k7 = k & 7;
        float bp = bcast8(A[tr][k], k7);
        float r  = __builtin_amdgcn_rcpf(bp);
        lacc += __log2f(fabsf(bp));

        float m[4];
        m[tr] = (h > k7) ? A[tr][k] * r : ((h == k7) ? (1.0f - r) : 0.0f);
        #pragma unroll
        for (int q = tr + 1; q < 4; ++q) m[q] = A[q][k] * r;

        float bq = bcast8(y[tr], k7);
        #pragma unroll
        for (int q = tr; q < 4; ++q) y[q] = fmaf(-m[q], bq, y[q]);

        const int j0 = k + 1;
        const int ja = (j0 + 3) & ~3;
        const int jh = (ja < CDIM) ? ja : CDIM;
        #pragma unroll
        for (int j = j0; j < jh; ++j) {       // head singles to 4-alignment
            float bv = bcast8(A[tr][j], k7);
            #pragma unroll
            for (int q = tr; q < 4; ++q)
                A[q][j] = fmaf(-m[q], bv, A[q][j]);
        }
        #pragma unroll
        for (int jb = jh; jb < CDIM; jb += 4) {   // 4-wide batches
            float u0 = bcast8(A[tr][jb + 0], k7);
            float u1 = bcast8(A[tr][jb + 1], k7);
            float u2 = bcast8(A[tr][jb + 2], k7);
            float u3 = bcast8(A[tr][jb + 3], k7);
            #pragma unroll
            for (int q = tr; q < 4; ++q) {
                A[q][jb + 0] = fmaf(-m[q], u0, A[q][jb + 0]);
                A[q][jb + 1] = fmaf(-m[q], u1, A[q][jb + 1]);
                A[q][jb + 2] = fmaf(-m[q], u2, A[q][jb + 2]);
                A[q][jb + 3] = fmaf(-m[q], u3, A[q][jb + 3]);
            }
        }
    }

    // ---- back-substitution (unit-diagonal U after owner scaling) ----
    #pragma unroll
    for (int k = CDIM - 1; k >= 1; --k) {
        const int tr = k >> 3, k7 = k & 7;
        float bz = bcast8(y[tr], k7);      // z[k] (rows finalize high->low)
        float cm = (h < k7) ? A[tr][k] : 0.0f;  // owner & done rows: no-op
        y[tr] = fmaf(-cm, bz, y[tr]);
        #pragma unroll
        for (int q = 0; q < tr; ++q)
            y[q] = fmaf(-A[q][k], bz, y[q]);
    }
    // y[r] = z[8r + h]

    // ---- store z (dense 32B-segment pattern) ----
    float* zp = out + (size_t)b * CDIM * HWDIM + (size_t)h * HWDIM + pix;
    #pragma unroll
    for (int r = 0; r < 4; ++r) zp[(size_t)(r * 8) * HWDIM] = y[r];

    // ---- logdet: lacc identical across a pixel's 8 lanes; 3 xor-shuffles
    // sum the wave's 8 pixel-groups; one atomic per wave. ----
    float v2 = lacc;
    v2 += __shfl_xor(v2, 8);
    v2 += __shfl_xor(v2, 16);
    v2 += __shfl_xor(v2, 32);
    if (lane == 0) {
        float add = -v2 * 0.69314718055994531f;  // ln2 * sum(log2|piv|)
        if (pix0 == 0) add += logdet[b];         // exactly one wave per b
        atomicAdd(&out[ZOFF + b], add);
    }
}

extern "C" void kernel_launch(void* const* d_in, const int* in_sizes, int n_in,
                              void* d_out, int out_size, void* d_ws, size_t ws_size,
                              hipStream_t stream) {
    const float* input  = (const float*)d_in[0];
    const float* weight = (const float*)d_in[1];
    const float* logdet = (const float*)d_in[2];
    float* out = (float*)d_out;

    solve_kernel<<<BDIM * (HWDIM / PPB), NTHREADS, 0, stream>>>(input, weight,
                                                                logdet, out);
}

// Round 14
// 1042.628 us; speedup vs baseline: 1.0013x; 1.0013x over previous
//
#include <hip/hip_runtime.h>
#include <math.h>

#define CDIM 32
#define HWDIM 2304            // 48*48
#define BDIM 16
#define PPW 8                 // pixels per wave (8 lanes per pixel)
#define NTHREADS 256          // 4 waves => 32 pixels per block
#define PPB 32
#define ZOFF (BDIM * CDIM * HWDIM)   // z elements, then 16 logdet floats

// R13 lesson (resolves the 4-spill pattern): right-looking + pure-DPP
// broadcasts expose ~28 independent ops per k-step; LLVM's pre-RA scheduler
// hoists them across k-steps without bound -> live-range explosion -> A
// spilled wholesale (WRITE 1.76GB). __shfl variants never spilled (bpermute
// is a convergent memory op, motion-fenced); left-looking DPP (R7) had
// nothing to hoist. R14 = R13 + __builtin_amdgcn_sched_barrier(0) at the
// end of every k-step: motion bounded to one step (pressure ~150 < 256),
// ILP within the step preserved (8 indep DPP + 10-16 indep fmas per 4-wide
// batch). Zero runtime cost; finally runs the dependency-vs-fetch test.
__device__ __forceinline__ void gload_lds16(const float* g, float* l) {
    __builtin_amdgcn_global_load_lds(
        (const __attribute__((address_space(1))) float*)g,
        (__attribute__((address_space(3))) float*)l, 16, 0, 0);
}

// Broadcast lane (group_base + k7) to all 8 lanes of each aligned 8-lane
// group (R7-proven DPP pair; k7 compile-time, call sites fully unrolled).
// Step1 quad_perm([s,s,s,s]), s=k7&3. Step2: k7<4: row_shr:4 mask 0xA
// (odd quads <- even); k7>=4: row_shl:4 mask 0x5 (even <- odd).
__device__ __forceinline__ float bcast8(float x, int k7) {
    int v = __float_as_int(x), b;
    switch (k7) {
    case 0: b = __builtin_amdgcn_update_dpp(v, v, 0x00, 0xF, 0xF, false);
            b = __builtin_amdgcn_update_dpp(b, b, 0x114, 0xF, 0xA, false); break;
    case 1: b = __builtin_amdgcn_update_dpp(v, v, 0x55, 0xF, 0xF, false);
            b = __builtin_amdgcn_update_dpp(b, b, 0x114, 0xF, 0xA, false); break;
    case 2: b = __builtin_amdgcn_update_dpp(v, v, 0xAA, 0xF, 0xF, false);
            b = __builtin_amdgcn_update_dpp(b, b, 0x114, 0xF, 0xA, false); break;
    case 3: b = __builtin_amdgcn_update_dpp(v, v, 0xFF, 0xF, 0xF, false);
            b = __builtin_amdgcn_update_dpp(b, b, 0x114, 0xF, 0xA, false); break;
    case 4: b = __builtin_amdgcn_update_dpp(v, v, 0x00, 0xF, 0xF, false);
            b = __builtin_amdgcn_update_dpp(b, b, 0x104, 0xF, 0x5, false); break;
    case 5: b = __builtin_amdgcn_update_dpp(v, v, 0x55, 0xF, 0xF, false);
            b = __builtin_amdgcn_update_dpp(b, b, 0x104, 0xF, 0x5, false); break;
    case 6: b = __builtin_amdgcn_update_dpp(v, v, 0xAA, 0xF, 0xF, false);
            b = __builtin_amdgcn_update_dpp(b, b, 0x104, 0xF, 0x5, false); break;
    default: b = __builtin_amdgcn_update_dpp(v, v, 0xFF, 0xF, 0xF, false);
            b = __builtin_amdgcn_update_dpp(b, b, 0x104, 0xF, 0x5, false); break;
    }
    return __int_as_float(b);
}

__global__ __launch_bounds__(NTHREADS, 2)
void solve_kernel(const float* __restrict__ input,
                  const float* __restrict__ weight,
                  const float* __restrict__ logdet,
                  float* __restrict__ out) {
    const int t    = threadIdx.x;
    const int lane = t & 63;
    const int wv   = t >> 6;           // wave 0..3
    const int h    = lane & 7;         // row class: owns rows i = 8r + h
    const int p    = lane >> 3;        // pixel-in-wave 0..7

    const int blk  = blockIdx.x;
    const int b    = blk / (HWDIM / PPB);       // 72 blocks per batch image
    const int pb   = (blk % (HWDIM / PPB)) * PPB;  // block pixel base
    const int pixl = wv * PPW + p;              // pixel-in-block 0..31
    const int pix0 = pb + wv * PPW;             // wave pixel base (logdet cond)
    const int pix  = pb + pixl;

    __shared__ float lds[2][256 * CDIM];        // 2 x 32KB chunk ring

    // ---- x: scalar loads, issued first (oldest in vmcnt order) ----
    const float* xp = input + (size_t)b * CDIM * HWDIM + (size_t)h * HWDIM + pix;
    float y[4];
    #pragma unroll
    for (int r = 0; r < 4; ++r) y[r] = xp[(size_t)(r * 8) * HWDIM];
    asm volatile("" ::: "memory");     // pin: x loads oldest in vmcnt order

    // ---- DMA staging (R3-verbatim): chunk r = rc-rows [256r, 256r+256) ----
    // rcl = wv*64 + q*8 + sg; LDS dest linear (word rcl*32 + sp*4); global
    // source slot pre-swizzled by g = rcl>>5 (wave-uniform per q -> full
    // 128B lines). Read: A[r][j] at word (h*32+j)*32 + ((ps^h)<<2)+pc.
    const int sg = lane >> 3;
    const int sp = lane & 7;
    const int ps = pixl >> 2, pc = pixl & 3;
    const float* wbase = weight + (size_t)b * (CDIM * CDIM) * HWDIM + pb;
    const float* srcA = wbase + (size_t)(wv * 64 + sg) * HWDIM
                              + ((sp ^ (2 * wv)) << 2);
    const float* srcB = wbase + (size_t)(wv * 64 + sg) * HWDIM
                              + ((sp ^ (2 * wv + 1)) << 2);

    auto stage = [&](int r, int buf) {
        float* lbase = &lds[buf][(wv * 64) * CDIM];
        #pragma unroll
        for (int q = 0; q < 8; ++q) {
            const float* s = (q < 4 ? srcA : srcB)
                           + (size_t)(r * 256 + q * 8) * HWDIM;
            gload_lds16(s, lbase + q * 8 * CDIM);
        }
    };

    stage(0, 0);
    asm volatile("" ::: "memory");
    stage(1, 1);

    float A[4][CDIM];
    #pragma unroll
    for (int r = 0; r < 4; ++r) {
        if (r < 3) asm volatile("s_waitcnt vmcnt(8)" ::: "memory");
        else       asm volatile("s_waitcnt vmcnt(0)" ::: "memory");
        __builtin_amdgcn_s_barrier();
        asm volatile("" ::: "memory");
        #pragma unroll
        for (int j = 0; j < CDIM; ++j)
            A[r][j] = lds[r & 1][(h * CDIM + j) * CDIM + ((ps ^ h) << 2) + pc];
        if (r < 2) {
            asm volatile("s_waitcnt lgkmcnt(0)" ::: "memory");
            __builtin_amdgcn_s_barrier();
            asm volatile("" ::: "memory");
            stage(r + 2, r & 1);
        }
    }

    // ---- right-looking LU, no pivoting (R3-verbatim algebra; owner row
    // scaled to unit diagonal via m_owner = 1-r). 4-wide j-batches give the
    // in-order wave 8 independent DPP movs + 10-16 independent fmas per
    // batch; a sched_barrier(0) per k-step stops cross-step hoisting.
    float lacc = 0.0f;
    #pragma unroll
    for (int k = 0; k < CDIM; ++k) {
        const int tr = k >> 3, k7 = k & 7;
        float bp = bcast8(A[tr][k], k7);
        float r  = __builtin_amdgcn_rcpf(bp);
        lacc += __log2f(fabsf(bp));

        float m[4];
        m[tr] = (h > k7) ? A[tr][k] * r : ((h == k7) ? (1.0f - r) : 0.0f);
        #pragma unroll
        for (int q = tr + 1; q < 4; ++q) m[q] = A[q][k] * r;

        float bq = bcast8(y[tr], k7);
        #pragma unroll
        for (int q = tr; q < 4; ++q) y[q] = fmaf(-m[q], bq, y[q]);

        const int j0 = k + 1;
        const int ja = (j0 + 3) & ~3;
        const int jh = (ja < CDIM) ? ja : CDIM;
        #pragma unroll
        for (int j = j0; j < jh; ++j) {       // head singles to 4-alignment
            float bv = bcast8(A[tr][j], k7);
            #pragma unroll
            for (int q = tr; q < 4; ++q)
                A[q][j] = fmaf(-m[q], bv, A[q][j]);
        }
        #pragma unroll
        for (int jb = jh; jb < CDIM; jb += 4) {   // 4-wide batches
            float u0 = bcast8(A[tr][jb + 0], k7);
            float u1 = bcast8(A[tr][jb + 1], k7);
            float u2 = bcast8(A[tr][jb + 2], k7);
            float u3 = bcast8(A[tr][jb + 3], k7);
            #pragma unroll
            for (int q = tr; q < 4; ++q) {
                A[q][jb + 0] = fmaf(-m[q], u0, A[q][jb + 0]);
                A[q][jb + 1] = fmaf(-m[q], u1, A[q][jb + 1]);
                A[q][jb + 2] = fmaf(-m[q], u2, A[q][jb + 2]);
                A[q][jb + 3] = fmaf(-m[q], u3, A[q][jb + 3]);
            }
        }
        // fence scheduler motion at the k-step boundary: keeps register
        // pressure bounded to one step's working set (the R13 spill fix).
        __builtin_amdgcn_sched_barrier(0);
    }

    // ---- back-substitution (unit-diagonal U after owner scaling) ----
    #pragma unroll
    for (int k = CDIM - 1; k >= 1; --k) {
        const int tr = k >> 3, k7 = k & 7;
        float bz = bcast8(y[tr], k7);      // z[k] (rows finalize high->low)
        float cm = (h < k7) ? A[tr][k] : 0.0f;  // owner & done rows: no-op
        y[tr] = fmaf(-cm, bz, y[tr]);
        #pragma unroll
        for (int q = 0; q < tr; ++q)
            y[q] = fmaf(-A[q][k], bz, y[q]);
    }
    // y[r] = z[8r + h]

    // ---- store z (dense 32B-segment pattern) ----
    float* zp = out + (size_t)b * CDIM * HWDIM + (size_t)h * HWDIM + pix;
    #pragma unroll
    for (int r = 0; r < 4; ++r) zp[(size_t)(r * 8) * HWDIM] = y[r];

    // ---- logdet: lacc identical across a pixel's 8 lanes; 3 xor-shuffles
    // sum the wave's 8 pixel-groups; one atomic per wave. ----
    float v2 = lacc;
    v2 += __shfl_xor(v2, 8);
    v2 += __shfl_xor(v2, 16);
    v2 += __shfl_xor(v2, 32);
    if (lane == 0) {
        float add = -v2 * 0.69314718055994531f;  // ln2 * sum(log2|piv|)
        if (pix0 == 0) add += logdet[b];         // exactly one wave per b
        atomicAdd(&out[ZOFF + b], add);
    }
}

extern "C" void kernel_launch(void* const* d_in, const int* in_sizes, int n_in,
                              void* d_out, int out_size, void* d_ws, size_t ws_size,
                              hipStream_t stream) {
    const float* input  = (const float*)d_in[0];
    const float* weight = (const float*)d_in[1];
    const float* logdet = (const float*)d_in[2];
    float* out = (float*)d_out;

    solve_kernel<<<BDIM * (HWDIM / PPB), NTHREADS, 0, stream>>>(input, weight,
                                                                logdet, out);
}

// Round 15
// 401.558 us; speedup vs baseline: 2.5999x; 2.5965x over previous
//
#include <hip/hip_runtime.h>
#include <math.h>

#define CDIM 32
#define HWDIM 2304            // 48*48
#define BDIM 16
#define PPW 8                 // pixels per wave (8 lanes per pixel)
#define NTHREADS 256          // 4 waves => 32 pixels per block
#define PPB 32
#define ZOFF (BDIM * CDIM * HWDIM)   // z elements, then 16 logdet floats

// R14 lesson: sched_barrier changed NOTHING vs R13 (byte-identical
// counters) -> the 1.76GB spill was an SROA failure (computed loop bounds
// left A runtime-indexed -> scratch-resident from the start), not scheduler
// motion. Clean kernels (R3/R5/R7) all share the plain loop forms this
// compiler provably promotes.
// R15 = R3 VERBATIM (proven clean: VGPR 88, WRITE 4752KB, 121us) with
// exactly ONE change: __shfl(x, gb+k7) -> bcast8(x, k7) (R7-proven DPP
// pair; k7 compile-time after unroll). Right-looking's independent
// j-updates + latency-free broadcasts, in a shell that compiles clean.
__device__ __forceinline__ void gload_lds16(const float* g, float* l) {
    __builtin_amdgcn_global_load_lds(
        (const __attribute__((address_space(1))) float*)g,
        (__attribute__((address_space(3))) float*)l, 16, 0, 0);
}

// Broadcast lane (group_base + k7) to all 8 lanes of each aligned 8-lane
// group (R7-proven DPP pair; k7 compile-time, call sites fully unrolled).
// Step1 quad_perm([s,s,s,s]), s=k7&3. Step2: k7<4: row_shr:4 mask 0xA
// (odd quads <- even); k7>=4: row_shl:4 mask 0x5 (even <- odd).
__device__ __forceinline__ float bcast8(float x, int k7) {
    int v = __float_as_int(x), b;
    switch (k7) {
    case 0: b = __builtin_amdgcn_update_dpp(v, v, 0x00, 0xF, 0xF, false);
            b = __builtin_amdgcn_update_dpp(b, b, 0x114, 0xF, 0xA, false); break;
    case 1: b = __builtin_amdgcn_update_dpp(v, v, 0x55, 0xF, 0xF, false);
            b = __builtin_amdgcn_update_dpp(b, b, 0x114, 0xF, 0xA, false); break;
    case 2: b = __builtin_amdgcn_update_dpp(v, v, 0xAA, 0xF, 0xF, false);
            b = __builtin_amdgcn_update_dpp(b, b, 0x114, 0xF, 0xA, false); break;
    case 3: b = __builtin_amdgcn_update_dpp(v, v, 0xFF, 0xF, 0xF, false);
            b = __builtin_amdgcn_update_dpp(b, b, 0x114, 0xF, 0xA, false); break;
    case 4: b = __builtin_amdgcn_update_dpp(v, v, 0x00, 0xF, 0xF, false);
            b = __builtin_amdgcn_update_dpp(b, b, 0x104, 0xF, 0x5, false); break;
    case 5: b = __builtin_amdgcn_update_dpp(v, v, 0x55, 0xF, 0xF, false);
            b = __builtin_amdgcn_update_dpp(b, b, 0x104, 0xF, 0x5, false); break;
    case 6: b = __builtin_amdgcn_update_dpp(v, v, 0xAA, 0xF, 0xF, false);
            b = __builtin_amdgcn_update_dpp(b, b, 0x104, 0xF, 0x5, false); break;
    default: b = __builtin_amdgcn_update_dpp(v, v, 0xFF, 0xF, 0xF, false);
            b = __builtin_amdgcn_update_dpp(b, b, 0x104, 0xF, 0x5, false); break;
    }
    return __int_as_float(b);
}

__global__ __launch_bounds__(NTHREADS, 2)
void solve_kernel(const float* __restrict__ input,
                  const float* __restrict__ weight,
                  const float* __restrict__ logdet,
                  float* __restrict__ out) {
    const int t    = threadIdx.x;
    const int lane = t & 63;
    const int wv   = t >> 6;           // wave 0..3
    const int h    = lane & 7;         // row class: owns rows i = 8r + h
    const int p    = lane >> 3;        // pixel-in-wave 0..7

    const int blk  = blockIdx.x;
    const int b    = blk / (HWDIM / PPB);       // 72 blocks per batch image
    const int pb   = (blk % (HWDIM / PPB)) * PPB;  // block pixel base
    const int pixl = wv * PPW + p;              // pixel-in-block 0..31
    const int pix0 = pb + wv * PPW;             // wave pixel base (logdet cond)
    const int pix  = pb + pixl;

    __shared__ float lds[2][256 * CDIM];        // 2 x 32KB chunk buffers

    // ---- x: scalar loads, issued first (oldest in vmcnt order) ----
    const float* xp = input + (size_t)b * CDIM * HWDIM + (size_t)h * HWDIM + pix;
    float y[4];
    #pragma unroll
    for (int r = 0; r < 4; ++r) y[r] = xp[(size_t)(r * 8) * HWDIM];
    asm volatile("" ::: "memory");     // pin: x loads oldest in vmcnt order

    // ---- DMA staging (R3-verbatim): chunk r = rc-rows [256r, 256r+256) ----
    // rcl = wv*64 + q*8 + sg; LDS dest linear (word rcl*32 + sp*4); global
    // source slot pre-swizzled by g = rcl>>5 (wave-uniform per q -> full
    // 128B lines). Read: A[r][j] at word (h*32+j)*32 + ((ps^h)<<2)+pc.
    const int sg = lane >> 3;
    const int sp = lane & 7;
    const int ps = pixl >> 2, pc = pixl & 3;
    const float* wbase = weight + (size_t)b * (CDIM * CDIM) * HWDIM + pb;
    const float* srcA = wbase + (size_t)(wv * 64 + sg) * HWDIM
                              + ((sp ^ (2 * wv)) << 2);
    const float* srcB = wbase + (size_t)(wv * 64 + sg) * HWDIM
                              + ((sp ^ (2 * wv + 1)) << 2);

    auto stage = [&](int r, int buf) {
        float* lbase = &lds[buf][(wv * 64) * CDIM];
        #pragma unroll
        for (int q = 0; q < 8; ++q) {
            const float* s = (q < 4 ? srcA : srcB)
                           + (size_t)(r * 256 + q * 8) * HWDIM;
            gload_lds16(s, lbase + q * 8 * CDIM);
        }
    };

    stage(0, 0);
    asm volatile("" ::: "memory");     // pin: chunk0's 8 DMAs before chunk1's
    stage(1, 1);

    float A[4][CDIM];
    #pragma unroll
    for (int r = 0; r < 4; ++r) {
        if (r < 3) asm volatile("s_waitcnt vmcnt(8)" ::: "memory");
        else       asm volatile("s_waitcnt vmcnt(0)" ::: "memory");
        __builtin_amdgcn_s_barrier();
        asm volatile("" ::: "memory");   // keep ds_reads below the barrier
        #pragma unroll
        for (int j = 0; j < CDIM; ++j)
            A[r][j] = lds[r & 1][(h * CDIM + j) * CDIM + ((ps ^ h) << 2) + pc];
        if (r < 2) {
            asm volatile("s_waitcnt lgkmcnt(0)" ::: "memory");
            __builtin_amdgcn_s_barrier();
            asm volatile("" ::: "memory");
            stage(r + 2, r & 1);
        }
    }

    // ---- right-looking LU, no pivoting (R3-verbatim; owner row scaled to
    // unit diagonal via m_owner = 1-r). Only change: bcast8 not __shfl. ----
    float lacc = 0.0f;
    #pragma unroll
    for (int k = 0; k < CDIM; ++k) {
        const int tr = k >> 3, k7 = k & 7;
        float bp = bcast8(A[tr][k], k7);
        float r  = __builtin_amdgcn_rcpf(bp);
        lacc += __log2f(fabsf(bp));

        float m[4];
        m[tr] = (h > k7) ? A[tr][k] * r : ((h == k7) ? (1.0f - r) : 0.0f);
        #pragma unroll
        for (int q = tr + 1; q < 4; ++q) m[q] = A[q][k] * r;

        #pragma unroll
        for (int j = k + 1; j < CDIM; ++j) {
            float bv = bcast8(A[tr][j], k7);
            #pragma unroll
            for (int q = tr; q < 4; ++q)
                A[q][j] = fmaf(-m[q], bv, A[q][j]);
        }
        float bq = bcast8(y[tr], k7);
        #pragma unroll
        for (int q = tr; q < 4; ++q) y[q] = fmaf(-m[q], bq, y[q]);
    }

    // ---- back-substitution (unit-diagonal U after owner scaling) ----
    #pragma unroll
    for (int k = CDIM - 1; k >= 1; --k) {
        const int tr = k >> 3, k7 = k & 7;
        float bz = bcast8(y[tr], k7);      // z[k] (rows finalize high->low)
        float c = (h < k7) ? A[tr][k] : 0.0f;   // owner & done rows: no-op
        y[tr] = fmaf(-c, bz, y[tr]);
        #pragma unroll
        for (int q = 0; q < tr; ++q)
            y[q] = fmaf(-A[q][k], bz, y[q]);
    }
    // y[r] = z[8r + h]

    // ---- store z (dense 32B-segment pattern) ----
    float* zp = out + (size_t)b * CDIM * HWDIM + (size_t)h * HWDIM + pix;
    #pragma unroll
    for (int r = 0; r < 4; ++r) zp[(size_t)(r * 8) * HWDIM] = y[r];

    // ---- logdet: lacc is identical across a pixel's 8 lanes; sum the wave's
    // 8 pixel-groups via 3 xor-shuffles, one atomic per wave. ----
    float v2 = lacc;
    v2 += __shfl_xor(v2, 8);
    v2 += __shfl_xor(v2, 16);
    v2 += __shfl_xor(v2, 32);
    if (lane == 0) {
        float add = -v2 * 0.69314718055994531f;  // ln2 * sum(log2|piv|)
        if (pix0 == 0) add += logdet[b];         // exactly one wave per b
        atomicAdd(&out[ZOFF + b], add);
    }
}

extern "C" void kernel_launch(void* const* d_in, const int* in_sizes, int n_in,
                              void* d_out, int out_size, void* d_ws, size_t ws_size,
                              hipStream_t stream) {
    const float* input  = (const float*)d_in[0];
    const float* weight = (const float*)d_in[1];
    const float* logdet = (const float*)d_in[2];
    float* out = (float*)d_out;

    solve_kernel<<<BDIM * (HWDIM / PPB), NTHREADS, 0, stream>>>(input, weight,
                                                                logdet, out);
}